// Round 5
// baseline (464.952 us; speedup 1.0000x reference)
//
#include <hip/hip_runtime.h>
#include <hip/hip_cooperative_groups.h>
#include <hip/hip_bf16.h>
#include <math.h>

namespace cg = cooperative_groups;

#define Bn 16
#define Pn 500
#define Nn 501
#define En 128
#define Hn 8
#define Ln 3
#define ROWS (Bn*Nn)   // 8016
#define LN_EPS 1e-5f

typedef __attribute__((ext_vector_type(8))) short bf16x8;
typedef __attribute__((ext_vector_type(4))) float f32x4;

__device__ inline short f2bf(float x) {
  __hip_bfloat16 h = __float2bfloat16(x);
  return *reinterpret_cast<short*>(&h);
}
__device__ inline float bf2f(short s) {
  __hip_bfloat16 h = *reinterpret_cast<__hip_bfloat16*>(&s);
  return __bfloat162float(h);
}

// ---- shared-memory union: gemm phase vs attn phase ----
struct SmemGemm {
  float Bs[32][128];   // W k-slice
  float As[32][33];    // x k-slice
  float xt[32][132];   // xW tile for eij epilogue
};
struct SmemAttn {
  float ejl[Hn][516];
  float Vt[64][132];
  unsigned adjw[32][17];
  float oout[32][132];
};
union Smem { SmemGemm g; SmemAttn a; };

__global__ __launch_bounds__(512) void mega_kernel(
    const float* __restrict__ depot, const float* __restrict__ node,
    const int* __restrict__ adj,
    const float* __restrict__ depW, const float* __restrict__ depB,
    const float* __restrict__ nodeW, const float* __restrict__ nodeB,
    const float* __restrict__ W, const float* __restrict__ attnw,
    const float* __restrict__ lng, const float* __restrict__ lnb,
    float* __restrict__ out,
    float* __restrict__ xa, float* __restrict__ xw,
    float* __restrict__ ei, float* __restrict__ ej,
    unsigned* __restrict__ adjbits) {
  cg::grid_group gg = cg::this_grid();
  __shared__ Smem sm;
  const int blk = blockIdx.x;
  const int t = threadIdx.x;

  // ================= P0a: adjacency bit-pack =================
  {
    int lanebit = t & 63, wave = t >> 6;
    for (int r = 0; r < 32; ++r) {
      int row = blk * 32 + r;
      if (row >= ROWS) break;
      int v = (t < Nn) ? adj[(size_t)row * Nn + t] : 0;
      unsigned long long mask = __ballot(v != 0);
      if (lanebit == 0) {
        int b = row / Nn, i = row - b * Nn;
        unsigned* wp = adjbits + ((size_t)(b * 512 + i)) * 16 + wave * 2;
        wp[0] = (unsigned)(mask & 0xffffffffull);
        wp[1] = (unsigned)(mask >> 32);
      }
    }
  }
  // ================= P0b: embedding =================
  {
#pragma unroll
    for (int s = 0; s < 8; ++s) {
      int idx = (blk * 512 + t) + s * 131072;  // 256*512
      if (idx < ROWS * En) {
        int row = idx >> 7, e = idx & 127;
        int b = row / Nn, n = row - b * Nn;
        float v;
        if (n == 0) {
          v = depB[e] + depot[b * 2 + 0] * depW[0 * En + e]
                      + depot[b * 2 + 1] * depW[1 * En + e];
        } else {
          const float* np_ = node + ((size_t)b * Pn + (n - 1)) * 5;
          v = nodeB[e];
#pragma unroll
          for (int k = 0; k < 5; k++) v += np_[k] * nodeW[k * En + e];
        }
        xa[idx] = v;
      }
    }
  }
  gg.sync();

  for (int l = 0; l < Ln; ++l) {
    const float* Wl = W + (size_t)l * En * En;
    const float* al = attnw + (size_t)l * Hn * 32;
    const float* g  = lng + (size_t)l * En;
    const float* bb = lnb + (size_t)l * En;
    float* dst = (l == Ln - 1) ? out : xa;

    // ================= P1: xw = xa @ Wl (+ eij epilogue) =================
    {
      int row0 = blk * 32;
      if (row0 < ROWS) {
        int tc = t & 31, tr = t >> 5;   // tc: col group of 4; tr: row pair
        float acc[2][4] = {{0.f,0.f,0.f,0.f},{0.f,0.f,0.f,0.f}};
        for (int k0 = 0; k0 < 128; k0 += 32) {
          {
            int r0 = t >> 5, c0 = t & 31;
            int gr = row0 + r0;
            sm.g.As[r0][c0] = (gr < ROWS) ? xa[(size_t)gr * 128 + k0 + c0] : 0.f;
            int s1 = t + 512;
            int r1 = s1 >> 5, c1 = s1 & 31;
            gr = row0 + r1;
            sm.g.As[r1][c1] = (gr < ROWS) ? xa[(size_t)gr * 128 + k0 + c1] : 0.f;
          }
#pragma unroll
          for (int s = 0; s < 8; ++s) {
            int a2 = t + s * 512, r = a2 >> 7, c = a2 & 127;
            sm.g.Bs[r][c] = Wl[(k0 + r) * 128 + c];
          }
          __syncthreads();
#pragma unroll
          for (int kk = 0; kk < 32; ++kk) {
            float4 bv = *(float4*)&sm.g.Bs[kk][tc * 4];
            float av0 = sm.g.As[tr * 2][kk];
            float av1 = sm.g.As[tr * 2 + 1][kk];
            acc[0][0] += av0 * bv.x; acc[0][1] += av0 * bv.y;
            acc[0][2] += av0 * bv.z; acc[0][3] += av0 * bv.w;
            acc[1][0] += av1 * bv.x; acc[1][1] += av1 * bv.y;
            acc[1][2] += av1 * bv.z; acc[1][3] += av1 * bv.w;
          }
          __syncthreads();
        }
#pragma unroll
        for (int m = 0; m < 2; ++m) {
          int lr = tr * 2 + m;
          int gr = row0 + lr;
          float4 vv = make_float4(acc[m][0], acc[m][1], acc[m][2], acc[m][3]);
          *(float4*)&sm.g.xt[lr][tc * 4] = vv;
          if (gr < ROWS) *(float4*)&xw[(size_t)gr * 128 + tc * 4] = vv;
        }
        __syncthreads();
        // eij epilogue: 32 rows x 8 heads x {ei,ej}
        {
          int r = t >> 4, rest = t & 15;
          int h = rest >> 1, sel = rest & 1;
          int gr = row0 + r;
          if (gr < ROWS) {
            const float* av = al + h * 32 + sel * 16;
            float ssum = 0.f;
#pragma unroll
            for (int d = 0; d < 16; ++d) ssum += sm.g.xt[r][h * 16 + d] * av[d];
            (sel ? ej : ei)[(size_t)gr * 8 + h] = ssum;
          }
        }
      }
    }
    gg.sync();

    // ================= P2: flash attention + residual + LN + ELU =================
    {
      int b = blk >> 4;
      int i0 = (blk & 15) << 5;
      int h = t >> 6;
      int lane = t & 63;
      int li = lane & 15;
      int lg = lane >> 4;

      for (int s = t; s < 512 * Hn; s += 512) {
        int j = s >> 3, hh = s & 7;
        sm.a.ejl[hh][j] = (j < Nn) ? ej[((size_t)b * Nn + j) * Hn + hh] : 0.f;
      }
      for (int s = t; s < 32 * 16; s += 512) {
        int r = s >> 4, w = s & 15;
        int gi = i0 + r; if (gi >= Nn) gi = Nn - 1;
        sm.a.adjw[r][w] = adjbits[((size_t)b * 512 + gi) * 16 + w];
      }

      int gi0 = i0 + li;      if (gi0 >= Nn) gi0 = Nn - 1;
      int gi1 = i0 + 16 + li; if (gi1 >= Nn) gi1 = Nn - 1;
      float eiv0 = ei[((size_t)b * Nn + gi0) * Hn + h];
      float eiv1 = ei[((size_t)b * Nn + gi1) * Hn + h];

      f32x4 acc0 = {0.f, 0.f, 0.f, 0.f};
      f32x4 acc1 = {0.f, 0.f, 0.f, 0.f};
      float m0 = -1e30f, m1 = -1e30f, l0 = 0.f, l1 = 0.f;

      for (int jt = 0; jt < 8; ++jt) {
        int j0 = jt << 6;
        __syncthreads();
        for (int s = t; s < 64 * 32; s += 512) {
          int jj = s >> 5, c4 = (s & 31) << 2;
          int gj = j0 + jj;
          float4 v;
          if (gj < Nn) v = *(const float4*)&xw[((size_t)b * Nn + gj) * En + c4];
          else         v = make_float4(0.f, 0.f, 0.f, 0.f);
          *(float4*)&sm.a.Vt[jj][c4] = v;
        }
        __syncthreads();

        float sc0[2][8], sc1[2][8];
#pragma unroll
        for (int kw = 0; kw < 2; ++kw) {
          const float* pj = &sm.a.ejl[h][j0 + (kw << 5) + (lg << 3)];
          unsigned mb0 = (sm.a.adjw[li][(j0 >> 5) + kw] >> (lg << 3)) & 0xffu;
          unsigned mb1 = (sm.a.adjw[16 + li][(j0 >> 5) + kw] >> (lg << 3)) & 0xffu;
#pragma unroll
          for (int e = 0; e < 8; ++e) {
            float ejv = pj[e];
            float s0 = eiv0 + ejv; s0 = fmaxf(s0, 0.2f * s0);
            float s1 = eiv1 + ejv; s1 = fmaxf(s1, 0.2f * s1);
            sc0[kw][e] = ((mb0 >> e) & 1u) ? s0 : -INFINITY;
            sc1[kw][e] = ((mb1 >> e) & 1u) ? s1 : -INFINITY;
          }
        }
        float tm0 = -INFINITY, tm1 = -INFINITY;
#pragma unroll
        for (int kw = 0; kw < 2; ++kw)
#pragma unroll
          for (int e = 0; e < 8; ++e) {
            tm0 = fmaxf(tm0, sc0[kw][e]);
            tm1 = fmaxf(tm1, sc1[kw][e]);
          }
        tm0 = fmaxf(tm0, __shfl_xor(tm0, 16)); tm0 = fmaxf(tm0, __shfl_xor(tm0, 32));
        tm1 = fmaxf(tm1, __shfl_xor(tm1, 16)); tm1 = fmaxf(tm1, __shfl_xor(tm1, 32));
        float mn0 = fmaxf(m0, tm0), mn1 = fmaxf(m1, tm1);
        float fr0 = __expf(m0 - mn0), fr1 = __expf(m1 - mn1);
        m0 = mn0; m1 = mn1;

        float ts0 = 0.f, ts1 = 0.f;
        short ph0[2][8], pl0[2][8], ph1[2][8], pl1[2][8];
#pragma unroll
        for (int kw = 0; kw < 2; ++kw)
#pragma unroll
          for (int e = 0; e < 8; ++e) {
            float p0 = __expf(sc0[kw][e] - mn0);
            float p1 = __expf(sc1[kw][e] - mn1);
            ts0 += p0; ts1 += p1;
            short h0 = f2bf(p0); ph0[kw][e] = h0; pl0[kw][e] = f2bf(p0 - bf2f(h0));
            short h1 = f2bf(p1); ph1[kw][e] = h1; pl1[kw][e] = f2bf(p1 - bf2f(h1));
          }
        ts0 += __shfl_xor(ts0, 16); ts0 += __shfl_xor(ts0, 32);
        ts1 += __shfl_xor(ts1, 16); ts1 += __shfl_xor(ts1, 32);
        l0 = l0 * fr0 + ts0;
        l1 = l1 * fr1 + ts1;

        int base = lg << 2;
#pragma unroll
        for (int r = 0; r < 4; ++r) {
          acc0[r] *= __shfl(fr0, base + r);
          acc1[r] *= __shfl(fr1, base + r);
        }

#pragma unroll
        for (int kw = 0; kw < 2; ++kw) {
          short vh[8], vl[8];
#pragma unroll
          for (int e = 0; e < 8; ++e) {
            float v = sm.a.Vt[(kw << 5) + (lg << 3) + e][h * 16 + li];
            short hv = f2bf(v); vh[e] = hv; vl[e] = f2bf(v - bf2f(hv));
          }
          bf16x8 vbh = {vh[0], vh[1], vh[2], vh[3], vh[4], vh[5], vh[6], vh[7]};
          bf16x8 vbl = {vl[0], vl[1], vl[2], vl[3], vl[4], vl[5], vl[6], vl[7]};
          bf16x8 pah0 = {ph0[kw][0], ph0[kw][1], ph0[kw][2], ph0[kw][3],
                         ph0[kw][4], ph0[kw][5], ph0[kw][6], ph0[kw][7]};
          bf16x8 pal0 = {pl0[kw][0], pl0[kw][1], pl0[kw][2], pl0[kw][3],
                         pl0[kw][4], pl0[kw][5], pl0[kw][6], pl0[kw][7]};
          bf16x8 pah1 = {ph1[kw][0], ph1[kw][1], ph1[kw][2], ph1[kw][3],
                         ph1[kw][4], ph1[kw][5], ph1[kw][6], ph1[kw][7]};
          bf16x8 pal1 = {pl1[kw][0], pl1[kw][1], pl1[kw][2], pl1[kw][3],
                         pl1[kw][4], pl1[kw][5], pl1[kw][6], pl1[kw][7]};
          acc0 = __builtin_amdgcn_mfma_f32_16x16x32_bf16(pah0, vbh, acc0, 0, 0, 0);
          acc0 = __builtin_amdgcn_mfma_f32_16x16x32_bf16(pah0, vbl, acc0, 0, 0, 0);
          acc0 = __builtin_amdgcn_mfma_f32_16x16x32_bf16(pal0, vbh, acc0, 0, 0, 0);
          acc1 = __builtin_amdgcn_mfma_f32_16x16x32_bf16(pah1, vbh, acc1, 0, 0, 0);
          acc1 = __builtin_amdgcn_mfma_f32_16x16x32_bf16(pah1, vbl, acc1, 0, 0, 0);
          acc1 = __builtin_amdgcn_mfma_f32_16x16x32_bf16(pal1, vbh, acc1, 0, 0, 0);
        }
      }

      {
        int base = lg << 2;
#pragma unroll
        for (int r = 0; r < 4; ++r) {
          float d0 = __shfl(l0, base + r);
          float d1 = __shfl(l1, base + r);
          sm.a.oout[base + r][h * 16 + li] = acc0[r] / d0;
          sm.a.oout[16 + base + r][h * 16 + li] = acc1[r] / d1;
        }
      }
      __syncthreads();

      {
        int row = t >> 4;
        int c0 = (t & 15) << 3;
        int gi = i0 + row;
        bool valid = gi < Nn;
        int gic = valid ? gi : Nn - 1;
        const float* xr = &xw[((size_t)b * Nn + gic) * En + c0];
        float4 o1 = *(float4*)&sm.a.oout[row][c0];
        float4 o2 = *(float4*)&sm.a.oout[row][c0 + 4];
        float4 x1 = *(const float4*)xr;
        float4 x2 = *(const float4*)(xr + 4);
        float y[8];
        y[0] = o1.x + x1.x; y[1] = o1.y + x1.y; y[2] = o1.z + x1.z; y[3] = o1.w + x1.w;
        y[4] = o2.x + x2.x; y[5] = o2.y + x2.y; y[6] = o2.z + x2.z; y[7] = o2.w + x2.w;
        float sum = 0.f, sq = 0.f;
#pragma unroll
        for (int u = 0; u < 8; ++u) { sum += y[u]; sq += y[u] * y[u]; }
#pragma unroll
        for (int mk = 1; mk <= 8; mk <<= 1) {
          sum += __shfl_xor(sum, mk);
          sq  += __shfl_xor(sq, mk);
        }
        float mu = sum * (1.f / 128.f);
        float var = sq * (1.f / 128.f) - mu * mu;
        float rs = rsqrtf(var + LN_EPS);
        if (valid) {
          const float4 g1 = *(const float4*)&g[c0];
          const float4 g2 = *(const float4*)&g[c0 + 4];
          const float4 b1 = *(const float4*)&bb[c0];
          const float4 b2 = *(const float4*)&bb[c0 + 4];
          float gv[8] = {g1.x, g1.y, g1.z, g1.w, g2.x, g2.y, g2.z, g2.w};
          float bv[8] = {b1.x, b1.y, b1.z, b1.w, b2.x, b2.y, b2.z, b2.w};
          float* op = &dst[((size_t)b * Nn + gi) * En + c0];
          float zo[8];
#pragma unroll
          for (int u = 0; u < 8; ++u) {
            float z = (y[u] - mu) * rs * gv[u] + bv[u];
            zo[u] = (z > 0.f) ? z : expm1f(z);
          }
          *(float4*)op = make_float4(zo[0], zo[1], zo[2], zo[3]);
          *(float4*)(op + 4) = make_float4(zo[4], zo[5], zo[6], zo[7]);
        }
      }
    }
    if (l < Ln - 1) gg.sync();
  }
}

extern "C" void kernel_launch(void* const* d_in, const int* in_sizes, int n_in,
                              void* d_out, int out_size, void* d_ws, size_t ws_size,
                              hipStream_t stream) {
  const float* depot = (const float*)d_in[0];
  const float* node  = (const float*)d_in[1];
  const int*   adj   = (const int*)d_in[2];
  const float* depW  = (const float*)d_in[3];
  const float* depB  = (const float*)d_in[4];
  const float* nodeW = (const float*)d_in[5];
  const float* nodeB = (const float*)d_in[6];
  const float* W     = (const float*)d_in[7];
  const float* attnw = (const float*)d_in[8];
  const float* lng   = (const float*)d_in[9];
  const float* lnb   = (const float*)d_in[10];
  float* out = (float*)d_out;

  float* xa = (float*)d_ws;
  float* xw = xa + (size_t)ROWS * En;
  float* ei = xw + (size_t)ROWS * En;
  float* ej = ei + (size_t)ROWS * Hn;
  unsigned* adjbits = (unsigned*)(ej + (size_t)ROWS * Hn);

  void* args[] = {
    (void*)&depot, (void*)&node, (void*)&adj,
    (void*)&depW, (void*)&depB, (void*)&nodeW, (void*)&nodeB,
    (void*)&W, (void*)&attnw, (void*)&lng, (void*)&lnb,
    (void*)&out, (void*)&xa, (void*)&xw, (void*)&ei, (void*)&ej,
    (void*)&adjbits
  };
  hipLaunchCooperativeKernel((const void*)mega_kernel, dim3(256), dim3(512),
                             args, 0, stream);
}

// Round 6
// 330.769 us; speedup vs baseline: 1.4057x; 1.4057x over previous
//
#include <hip/hip_runtime.h>
#include <hip/hip_cooperative_groups.h>
#include <hip/hip_bf16.h>
#include <math.h>

namespace cg = cooperative_groups;

#define Bn 16
#define Pn 500
#define Nn 501
#define En 128
#define Hn 8
#define Ln 3
#define ROWS (Bn*Nn)   // 8016
#define LN_EPS 1e-5f

typedef __attribute__((ext_vector_type(8))) short bf16x8;
typedef __attribute__((ext_vector_type(4))) float f32x4;

__device__ inline float bfu2f(unsigned short u) {
  union { unsigned u32; float f; } c; c.u32 = ((unsigned)u) << 16; return c.f;
}
__device__ inline unsigned short f2bfu(float x) {
  __hip_bfloat16 h = __float2bfloat16(x);
  union { __hip_bfloat16 hh; unsigned short u; } c; c.hh = h; return c.u;
}

// LDS layout:
//   persistent: xt[32][132] f32 (x / xW / next-x), eit[32][8] f32, adjw[32][17] u32
//   union uni (141,312 B):
//     P1: Bs[128][132] f32 (67,584 B)
//     P2: VtT[128][520] bf16 (133,120 B) + ejl[8][512] bf16 (8,192 B)
//     LN: oout[32][132] f32 (aliases VtT start; guarded by __syncthreads)
#define UNI_BYTES 141312
#define EJL_OFF   133120

__global__ __launch_bounds__(512, 1) void mega_kernel(
    const float* __restrict__ depot, const float* __restrict__ node,
    const int* __restrict__ adj,
    const float* __restrict__ depW, const float* __restrict__ depB,
    const float* __restrict__ nodeW, const float* __restrict__ nodeB,
    const float* __restrict__ W, const float* __restrict__ attnw,
    const float* __restrict__ lng, const float* __restrict__ lnb,
    float* __restrict__ out,
    unsigned short* __restrict__ xwT,   // [16][128][512] bf16
    unsigned short* __restrict__ ejT) { // [16][8][512]  bf16
  cg::grid_group gg = cg::this_grid();

  __shared__ float xt[32][132];
  __shared__ float eit[32][8];
  __shared__ unsigned adjw[32][17];
  __shared__ __align__(16) char uni[UNI_BYTES];
  float* Bs = (float*)uni;                                   // [128][132]
  unsigned short* VtT = (unsigned short*)uni;                // [128][520]
  unsigned short* ejl = (unsigned short*)(uni + EJL_OFF);    // [8][512]
  float* oout = (float*)uni;                                 // [32][132]

  const int blk = blockIdx.x;
  const int t = threadIdx.x;
  const int b = blk >> 4;
  const int it = blk & 15;
  const int i0 = it << 5;
  const int rowb = b * Nn + i0;
  const int nval = (Nn - i0) < 32 ? (Nn - i0) : 32;
  const int wave = t >> 6, lane = t & 63;

  // ============ P0a: adjacency bitmask pack (block-local rows) ============
  for (int r4 = 0; r4 < 4; ++r4) {
    int r = wave * 4 + r4;
    int grow = rowb + r; if (grow >= ROWS) grow = ROWS - 1;
    const int* ar = adj + (size_t)grow * Nn;
    int v[8];
#pragma unroll
    for (int s = 0; s < 8; ++s) {
      int col = s * 64 + lane;
      v[s] = (col < Nn) ? ar[col] : 0;
    }
#pragma unroll
    for (int s = 0; s < 8; ++s) {
      unsigned long long mk = __ballot(v[s] != 0);
      if (lane == 0) {
        adjw[r][2 * s]     = (unsigned)(mk & 0xffffffffull);
        adjw[r][2 * s + 1] = (unsigned)(mk >> 32);
      }
    }
  }
  // ============ P0b: embedding -> xt (block-local rows) ============
#pragma unroll
  for (int s = 0; s < 8; ++s) {
    int idx = t + s * 512;          // 0..4095
    int r = idx >> 7, e = idx & 127;
    int n = i0 + r;
    float v = 0.f;
    if (r < nval) {
      if (n == 0) {
        v = depB[e] + depot[b * 2 + 0] * depW[0 * En + e]
                    + depot[b * 2 + 1] * depW[1 * En + e];
      } else {
        const float* np_ = node + ((size_t)b * Pn + (n - 1)) * 5;
        v = nodeB[e];
#pragma unroll
        for (int k = 0; k < 5; k++) v += np_[k] * nodeW[k * En + e];
      }
    }
    xt[r][e] = v;
  }
  // no grid sync needed: everything so far is block-local

  for (int l = 0; l < Ln; ++l) {
    const float* Wl = W + (size_t)l * En * En;
    const float* al = attnw + (size_t)l * Hn * 32;
    const float* g  = lng + (size_t)l * En;
    const float* bb = lnb + (size_t)l * En;

    // ================= P1: xW = xt @ Wl ; write xwT(bf16,T), ejT, eit =================
#pragma unroll
    for (int s = 0; s < 8; ++s) {
      int fidx = t + s * 512;       // 0..4095
      int r = fidx >> 5, c4 = (fidx & 31) << 2;
      *(f32x4*)&Bs[r * 132 + c4] = *(const f32x4*)&Wl[r * 128 + c4];
    }
    __syncthreads();   // Bs ready; xt stable (prev phase synced)

    {
      int tc = t & 31, tr2 = (t >> 5) << 1;
      f32x4 a0 = {0.f, 0.f, 0.f, 0.f}, a1 = {0.f, 0.f, 0.f, 0.f};
      for (int kk = 0; kk < 128; ++kk) {
        f32x4 bv = *(f32x4*)&Bs[kk * 132 + (tc << 2)];
        float av0 = xt[tr2][kk];
        float av1 = xt[tr2 + 1][kk];
        a0 += bv * av0;
        a1 += bv * av1;
      }
      __syncthreads();   // all xt reads done before overwrite
      f32x4 z4 = {0.f, 0.f, 0.f, 0.f};
      *(f32x4*)&xt[tr2][tc << 2]     = (tr2     < nval) ? a0 : z4;
      *(f32x4*)&xt[tr2 + 1][tc << 2] = (tr2 + 1 < nval) ? a1 : z4;
    }
    __syncthreads();     // new xt (= xW) ready

    // xwT: transposed bf16 write (coalesced 16B/thread)
    {
      int c = t >> 2, jg = t & 3;
      bf16x8 pk;
#pragma unroll
      for (int u = 0; u < 8; ++u) pk[u] = (short)f2bfu(xt[jg * 8 + u][c]);
      *(bf16x8*)&xwT[((size_t)(b * 128 + c)) * 512 + i0 + jg * 8] = pk;
    }
    // eij: ei -> eit (LDS), ej -> ejT (global bf16)
    {
      int r = t >> 4, rest = t & 15, h = rest >> 1, sel = rest & 1;
      const float* av = al + h * 32 + sel * 16;
      float ss = 0.f;
#pragma unroll
      for (int d = 0; d < 16; ++d) ss += xt[r][h * 16 + d] * av[d];
      if (sel) ejT[((size_t)(b * 8 + h)) * 512 + i0 + r] = f2bfu(r < nval ? ss : 0.f);
      else     eit[r][h] = ss;
    }
    gg.sync();   // xwT/ejT visible to all blocks of batch b

    // ================= P2: flash attention (all-LDS inner loop) =================
#pragma unroll
    for (int s = 0; s < 16; ++s) {
      int idx = t + s * 512;        // 0..8191
      int c = idx >> 6, j8 = (idx & 63) << 3;
      *(bf16x8*)&VtT[c * 520 + j8] =
          *(const bf16x8*)&xwT[((size_t)(b * 128 + c)) * 512 + j8];
    }
    {
      int hh = t >> 6, j8 = (t & 63) << 3;
      *(bf16x8*)&ejl[hh * 512 + j8] =
          *(const bf16x8*)&ejT[((size_t)(b * 8 + hh)) * 512 + j8];
    }
    __syncthreads();

    {
      const int h = wave;
      const int li = lane & 15, lg = lane >> 4;
      float eiv0 = eit[li][h];
      float eiv1 = eit[16 + li][h];
      f32x4 acc0 = {0.f, 0.f, 0.f, 0.f};
      f32x4 acc1 = {0.f, 0.f, 0.f, 0.f};
      float m0 = -1e30f, m1 = -1e30f, l0 = 0.f, l1 = 0.f;

      for (int jt = 0; jt < 8; ++jt) {
        int j0 = jt << 6;
        float sc0[2][8], sc1[2][8];
#pragma unroll
        for (int kw = 0; kw < 2; ++kw) {
          int jb = j0 + (kw << 5) + (lg << 3);
          bf16x8 ev = *(bf16x8*)&ejl[h * 512 + jb];
          unsigned mb0 = (adjw[li][(jt << 1) + kw] >> (lg << 3)) & 0xffu;
          unsigned mb1 = (adjw[16 + li][(jt << 1) + kw] >> (lg << 3)) & 0xffu;
#pragma unroll
          for (int e = 0; e < 8; ++e) {
            float ejv = bfu2f((unsigned short)ev[e]);
            float s0 = eiv0 + ejv; s0 = fmaxf(s0, 0.2f * s0);
            float s1 = eiv1 + ejv; s1 = fmaxf(s1, 0.2f * s1);
            sc0[kw][e] = ((mb0 >> e) & 1u) ? s0 : -INFINITY;
            sc1[kw][e] = ((mb1 >> e) & 1u) ? s1 : -INFINITY;
          }
        }
        float tm0 = -INFINITY, tm1 = -INFINITY;
#pragma unroll
        for (int kw = 0; kw < 2; ++kw)
#pragma unroll
          for (int e = 0; e < 8; ++e) {
            tm0 = fmaxf(tm0, sc0[kw][e]);
            tm1 = fmaxf(tm1, sc1[kw][e]);
          }
        tm0 = fmaxf(tm0, __shfl_xor(tm0, 16)); tm0 = fmaxf(tm0, __shfl_xor(tm0, 32));
        tm1 = fmaxf(tm1, __shfl_xor(tm1, 16)); tm1 = fmaxf(tm1, __shfl_xor(tm1, 32));
        float mn0 = fmaxf(m0, tm0), mn1 = fmaxf(m1, tm1);
        float fr0 = __expf(m0 - mn0), fr1 = __expf(m1 - mn1);
        m0 = mn0; m1 = mn1;

        float ts0 = 0.f, ts1 = 0.f;
        bf16x8 pah0[2], pal0[2], pah1[2], pal1[2];
#pragma unroll
        for (int kw = 0; kw < 2; ++kw)
#pragma unroll
          for (int e = 0; e < 8; ++e) {
            float p0 = __expf(sc0[kw][e] - mn0);
            float p1 = __expf(sc1[kw][e] - mn1);
            ts0 += p0; ts1 += p1;
            unsigned short h0 = f2bfu(p0);
            pah0[kw][e] = (short)h0; pal0[kw][e] = (short)f2bfu(p0 - bfu2f(h0));
            unsigned short h1 = f2bfu(p1);
            pah1[kw][e] = (short)h1; pal1[kw][e] = (short)f2bfu(p1 - bfu2f(h1));
          }
        ts0 += __shfl_xor(ts0, 16); ts0 += __shfl_xor(ts0, 32);
        ts1 += __shfl_xor(ts1, 16); ts1 += __shfl_xor(ts1, 32);
        l0 = l0 * fr0 + ts0;
        l1 = l1 * fr1 + ts1;

        int base = lg << 2;
#pragma unroll
        for (int r = 0; r < 4; ++r) {
          acc0[r] *= __shfl(fr0, base + r);
          acc1[r] *= __shfl(fr1, base + r);
        }
#pragma unroll
        for (int kw = 0; kw < 2; ++kw) {
          bf16x8 vb = *(bf16x8*)&VtT[(h * 16 + li) * 520 + j0 + (kw << 5) + (lg << 3)];
          acc0 = __builtin_amdgcn_mfma_f32_16x16x32_bf16(pah0[kw], vb, acc0, 0, 0, 0);
          acc0 = __builtin_amdgcn_mfma_f32_16x16x32_bf16(pal0[kw], vb, acc0, 0, 0, 0);
          acc1 = __builtin_amdgcn_mfma_f32_16x16x32_bf16(pah1[kw], vb, acc1, 0, 0, 0);
          acc1 = __builtin_amdgcn_mfma_f32_16x16x32_bf16(pal1[kw], vb, acc1, 0, 0, 0);
        }
      }
      __syncthreads();   // all V reads done before oout aliases VtT

      int base = lg << 2;
#pragma unroll
      for (int r = 0; r < 4; ++r) {
        float d0 = __shfl(l0, base + r);
        float d1 = __shfl(l1, base + r);
        oout[(base + r) * 132 + h * 16 + li] = acc0[r] / d0;
        oout[(16 + base + r) * 132 + h * 16 + li] = acc1[r] / d1;
      }
    }
    __syncthreads();

    // ================= LN: residual + LayerNorm + ELU =================
    {
      int row = t >> 4;
      int c0 = (t & 15) << 3;
      bool valid = row < nval;
      float4 o1 = *(float4*)&oout[row * 132 + c0];
      float4 o2 = *(float4*)&oout[row * 132 + c0 + 4];
      float4 x1 = *(float4*)&xt[row][c0];
      float4 x2 = *(float4*)&xt[row][c0 + 4];
      float y[8];
      y[0] = o1.x + x1.x; y[1] = o1.y + x1.y; y[2] = o1.z + x1.z; y[3] = o1.w + x1.w;
      y[4] = o2.x + x2.x; y[5] = o2.y + x2.y; y[6] = o2.z + x2.z; y[7] = o2.w + x2.w;
      float sum = 0.f, sq = 0.f;
#pragma unroll
      for (int u = 0; u < 8; ++u) { sum += y[u]; sq += y[u] * y[u]; }
#pragma unroll
      for (int mk = 1; mk <= 8; mk <<= 1) {
        sum += __shfl_xor(sum, mk);
        sq  += __shfl_xor(sq, mk);
      }
      float mu = sum * (1.f / 128.f);
      float var = sq * (1.f / 128.f) - mu * mu;
      float rs = rsqrtf(var + LN_EPS);
      float zo[8];
      const float4 g1 = *(const float4*)&g[c0];
      const float4 g2 = *(const float4*)&g[c0 + 4];
      const float4 b1 = *(const float4*)&bb[c0];
      const float4 b2 = *(const float4*)&bb[c0 + 4];
      float gv[8] = {g1.x, g1.y, g1.z, g1.w, g2.x, g2.y, g2.z, g2.w};
      float bv[8] = {b1.x, b1.y, b1.z, b1.w, b2.x, b2.y, b2.z, b2.w};
#pragma unroll
      for (int u = 0; u < 8; ++u) {
        float z = (y[u] - mu) * rs * gv[u] + bv[u];
        zo[u] = (z > 0.f) ? z : expm1f(z);
      }
      if (l == Ln - 1) {
        if (valid) {
          float* op = &out[((size_t)(rowb + row)) * En + c0];
          *(float4*)op = make_float4(zo[0], zo[1], zo[2], zo[3]);
          *(float4*)(op + 4) = make_float4(zo[4], zo[5], zo[6], zo[7]);
        }
      } else {
        // next-layer x back into xt (zeros for invalid rows)
#pragma unroll
        for (int u = 0; u < 8; ++u) xt[row][c0 + u] = valid ? zo[u] : 0.f;
      }
    }
    if (l < Ln - 1) gg.sync();  // protect xwT/ejT from next P1 overwrite
  }
}

extern "C" void kernel_launch(void* const* d_in, const int* in_sizes, int n_in,
                              void* d_out, int out_size, void* d_ws, size_t ws_size,
                              hipStream_t stream) {
  const float* depot = (const float*)d_in[0];
  const float* node  = (const float*)d_in[1];
  const int*   adj   = (const int*)d_in[2];
  const float* depW  = (const float*)d_in[3];
  const float* depB  = (const float*)d_in[4];
  const float* nodeW = (const float*)d_in[5];
  const float* nodeB = (const float*)d_in[6];
  const float* W     = (const float*)d_in[7];
  const float* attnw = (const float*)d_in[8];
  const float* lng   = (const float*)d_in[9];
  const float* lnb   = (const float*)d_in[10];
  float* out = (float*)d_out;

  unsigned short* xwT = (unsigned short*)d_ws;                 // 16*128*512 bf16
  unsigned short* ejT = xwT + (size_t)16 * 128 * 512;          // 16*8*512 bf16

  void* args[] = {
    (void*)&depot, (void*)&node, (void*)&adj,
    (void*)&depW, (void*)&depB, (void*)&nodeW, (void*)&nodeB,
    (void*)&W, (void*)&attnw, (void*)&lng, (void*)&lnb,
    (void*)&out, (void*)&xwT, (void*)&ejT
  };
  hipLaunchCooperativeKernel((const void*)mega_kernel, dim3(256), dim3(512),
                             args, 0, stream);
}

// Round 7
// 281.464 us; speedup vs baseline: 1.6519x; 1.1752x over previous
//
#include <hip/hip_runtime.h>
#include <hip/hip_cooperative_groups.h>
#include <hip/hip_bf16.h>
#include <math.h>

namespace cg = cooperative_groups;

#define Bn 16
#define Pn 500
#define Nn 501
#define En 128
#define Hn 8
#define Ln 3
#define ROWS (Bn*Nn)   // 8016
#define LN_EPS 1e-5f

typedef __attribute__((ext_vector_type(8))) short bf16x8;
typedef __attribute__((ext_vector_type(4))) float f32x4;

__device__ inline float bfu2f(unsigned short u) {
  union { unsigned u32; float f; } c; c.u32 = ((unsigned)u) << 16; return c.f;
}
__device__ inline unsigned short f2bfu(float x) {
  __hip_bfloat16 h = __float2bfloat16(x);
  union { __hip_bfloat16 hh; unsigned short u; } c; c.hh = h; return c.u;
}

// LDS: persistent xt[32][132] f32 + eit[32][8] + adjw[32][17]
// union uni (141,312 B): P1 Bs[128][132] f32 | P2 VtT[128][520] bf16 + ejl[8][512] bf16 | LN oout[32][132] f32
#define UNI_BYTES 141312
#define EJL_OFF   133120

__global__ __launch_bounds__(1024, 4) void mega_kernel(
    const float* __restrict__ depot, const float* __restrict__ node,
    const int* __restrict__ adj,
    const float* __restrict__ depW, const float* __restrict__ depB,
    const float* __restrict__ nodeW, const float* __restrict__ nodeB,
    const float* __restrict__ W, const float* __restrict__ attnw,
    const float* __restrict__ lng, const float* __restrict__ lnb,
    float* __restrict__ out,
    unsigned short* __restrict__ xwT0, unsigned short* __restrict__ ejT0,
    unsigned short* __restrict__ xwT1, unsigned short* __restrict__ ejT1) {
  cg::grid_group gg = cg::this_grid();

  __shared__ float xt[32][132];
  __shared__ float eit[32][8];
  __shared__ unsigned adjw[32][17];
  __shared__ __align__(16) char uni[UNI_BYTES];
  float* Bs = (float*)uni;                                   // [128][132]
  unsigned short* VtT = (unsigned short*)uni;                // [128][520]
  unsigned short* ejl = (unsigned short*)(uni + EJL_OFF);    // [8][512]
  float* oout = (float*)uni;                                 // [32][132]

  const int blk = blockIdx.x;
  const int t = threadIdx.x;
  const int b = blk >> 4;
  const int i0 = (blk & 15) << 5;
  const int rowb = b * Nn + i0;
  const int nval = (Nn - i0) < 32 ? (Nn - i0) : 32;
  const int wave = t >> 6, lane = t & 63;

  // ============ P0a: adjacency bitmask pack (16 waves x 2 rows) ============
#pragma unroll
  for (int r2 = 0; r2 < 2; ++r2) {
    int r = wave * 2 + r2;
    int grow = rowb + r; if (grow >= ROWS) grow = ROWS - 1;
    const int* ar = adj + (size_t)grow * Nn;
    int v[8];
#pragma unroll
    for (int s = 0; s < 8; ++s) {
      int col = s * 64 + lane;
      v[s] = (col < Nn) ? ar[col] : 0;
    }
#pragma unroll
    for (int s = 0; s < 8; ++s) {
      unsigned long long mk = __ballot(v[s] != 0);
      if (lane == 0) {
        adjw[r][2 * s]     = (unsigned)(mk & 0xffffffffull);
        adjw[r][2 * s + 1] = (unsigned)(mk >> 32);
      }
    }
  }
  // ============ P0b: embedding -> xt ============
#pragma unroll
  for (int s = 0; s < 4; ++s) {
    int idx = t + s * 1024;         // 0..4095
    int r = idx >> 7, e = idx & 127;
    int n = i0 + r;
    float v = 0.f;
    if (r < nval) {
      if (n == 0) {
        v = depB[e] + depot[b * 2 + 0] * depW[0 * En + e]
                    + depot[b * 2 + 1] * depW[1 * En + e];
      } else {
        const float* np_ = node + ((size_t)b * Pn + (n - 1)) * 5;
        v = nodeB[e];
#pragma unroll
        for (int k = 0; k < 5; k++) v += np_[k] * nodeW[k * En + e];
      }
    }
    xt[r][e] = v;
  }

  for (int l = 0; l < Ln; ++l) {
    const float* Wl = W + (size_t)l * En * En;
    const float* al = attnw + (size_t)l * Hn * 32;
    const float* g  = lng + (size_t)l * En;
    const float* bb = lnb + (size_t)l * En;
    unsigned short* xwT = (l & 1) ? xwT1 : xwT0;
    unsigned short* ejT = (l & 1) ? ejT1 : ejT0;

    // ================= P1: xW = xt @ Wl ; write xwT(bf16,T), ejT, eit =================
#pragma unroll
    for (int s = 0; s < 4; ++s) {
      int fidx = t + s * 1024;      // 0..4095
      int r = fidx >> 5, c4 = (fidx & 31) << 2;
      *(f32x4*)&Bs[r * 132 + c4] = *(const f32x4*)&Wl[r * 128 + c4];
    }
    __syncthreads();   // Bs ready; also covers P0b / prev-LN xt writes

    {
      int tc = t & 31, tr = t >> 5;   // 1 row x 4 cols per thread
      f32x4 a0 = {0.f, 0.f, 0.f, 0.f};
      for (int kk = 0; kk < 128; ++kk) {
        f32x4 bv = *(f32x4*)&Bs[kk * 132 + (tc << 2)];
        a0 += bv * xt[tr][kk];
      }
      __syncthreads();   // all xt reads done before overwrite
      f32x4 z4 = {0.f, 0.f, 0.f, 0.f};
      *(f32x4*)&xt[tr][tc << 2] = (tr < nval) ? a0 : z4;
    }
    __syncthreads();     // new xt (= xW) ready

    // xwT: transposed bf16 write (512 threads)
    if (t < 512) {
      int c = t >> 2, jg = t & 3;
      bf16x8 pk;
#pragma unroll
      for (int u = 0; u < 8; ++u) pk[u] = (short)f2bfu(xt[jg * 8 + u][c]);
      *(bf16x8*)&xwT[((size_t)(b * 128 + c)) * 512 + i0 + jg * 8] = pk;
    }
    // eij (512 threads): ei -> eit (LDS), ej -> ejT (global bf16)
    if (t < 512) {
      int r = t >> 4, rest = t & 15, h = rest >> 1, sel = rest & 1;
      const float* av = al + h * 32 + sel * 16;
      float ss = 0.f;
#pragma unroll
      for (int d = 0; d < 16; ++d) ss += xt[r][h * 16 + d] * av[d];
      if (sel) ejT[((size_t)(b * 8 + h)) * 512 + i0 + r] = f2bfu(r < nval ? ss : 0.f);
      else     eit[r][h] = ss;
    }
    gg.sync();   // xwT/ejT visible to all blocks of batch b

    // ================= P2: flash attention (all-LDS inner loop) =================
#pragma unroll
    for (int s = 0; s < 8; ++s) {
      int idx = t + s * 1024;       // 0..8191
      int c = idx >> 6, j8 = (idx & 63) << 3;
      *(bf16x8*)&VtT[c * 520 + j8] =
          *(const bf16x8*)&xwT[((size_t)(b * 128 + c)) * 512 + j8];
    }
    if (t < 512) {
      int hh = t >> 6, j8 = (t & 63) << 3;
      *(bf16x8*)&ejl[hh * 512 + j8] =
          *(const bf16x8*)&ejT[((size_t)(b * 8 + hh)) * 512 + j8];
    }
    __syncthreads();

    {
      const int h = wave >> 1;          // head
      const int rg = wave & 1;          // row-group (0: rows 0-15, 1: rows 16-31)
      const int li = lane & 15, lg = lane >> 4;
      const int r0 = rg << 4;
      float eiv0 = eit[r0 + li][h];
      f32x4 acc0 = {0.f, 0.f, 0.f, 0.f};
      float m0 = -1e30f, l0 = 0.f;

      for (int jt = 0; jt < 8; ++jt) {
        int j0 = jt << 6;
        float sc0[2][8];
#pragma unroll
        for (int kw = 0; kw < 2; ++kw) {
          int jb = j0 + (kw << 5) + (lg << 3);
          bf16x8 ev = *(bf16x8*)&ejl[h * 512 + jb];
          unsigned mb0 = (adjw[r0 + li][(jt << 1) + kw] >> (lg << 3)) & 0xffu;
#pragma unroll
          for (int e = 0; e < 8; ++e) {
            float ejv = bfu2f((unsigned short)ev[e]);
            float s0 = eiv0 + ejv; s0 = fmaxf(s0, 0.2f * s0);
            sc0[kw][e] = ((mb0 >> e) & 1u) ? s0 : -INFINITY;
          }
        }
        float tm0 = -INFINITY;
#pragma unroll
        for (int kw = 0; kw < 2; ++kw)
#pragma unroll
          for (int e = 0; e < 8; ++e) tm0 = fmaxf(tm0, sc0[kw][e]);
        tm0 = fmaxf(tm0, __shfl_xor(tm0, 16));
        tm0 = fmaxf(tm0, __shfl_xor(tm0, 32));
        float mn0 = fmaxf(m0, tm0);
        float fr0 = __expf(m0 - mn0);
        m0 = mn0;

        float ts0 = 0.f;
        bf16x8 pah0[2], pal0[2];
#pragma unroll
        for (int kw = 0; kw < 2; ++kw)
#pragma unroll
          for (int e = 0; e < 8; ++e) {
            float p0 = __expf(sc0[kw][e] - mn0);
            ts0 += p0;
            unsigned short h0 = f2bfu(p0);
            pah0[kw][e] = (short)h0;
            pal0[kw][e] = (short)f2bfu(p0 - bfu2f(h0));
          }
        ts0 += __shfl_xor(ts0, 16);
        ts0 += __shfl_xor(ts0, 32);
        l0 = l0 * fr0 + ts0;

        int base = lg << 2;
#pragma unroll
        for (int r = 0; r < 4; ++r) acc0[r] *= __shfl(fr0, base + r);

#pragma unroll
        for (int kw = 0; kw < 2; ++kw) {
          bf16x8 vb = *(bf16x8*)&VtT[(h * 16 + li) * 520 + j0 + (kw << 5) + (lg << 3)];
          acc0 = __builtin_amdgcn_mfma_f32_16x16x32_bf16(pah0[kw], vb, acc0, 0, 0, 0);
          acc0 = __builtin_amdgcn_mfma_f32_16x16x32_bf16(pal0[kw], vb, acc0, 0, 0, 0);
        }
      }
      __syncthreads();   // all V/ejl reads done before oout aliases VtT

      int base = lg << 2;
#pragma unroll
      for (int r = 0; r < 4; ++r) {
        float d0 = __shfl(l0, base + r);
        oout[(r0 + base + r) * 132 + h * 16 + li] = acc0[r] / d0;
      }
    }
    __syncthreads();

    // ================= LN: residual + LayerNorm + ELU (1 row x 4 cols/thread) =================
    {
      int row = t >> 5;
      int c0 = (t & 31) << 2;
      bool valid = row < nval;
      float4 o1 = *(float4*)&oout[row * 132 + c0];
      float4 x1 = *(float4*)&xt[row][c0];
      float y[4] = {o1.x + x1.x, o1.y + x1.y, o1.z + x1.z, o1.w + x1.w};
      float sum = 0.f, sq = 0.f;
#pragma unroll
      for (int u = 0; u < 4; ++u) { sum += y[u]; sq += y[u] * y[u]; }
#pragma unroll
      for (int mk = 1; mk <= 16; mk <<= 1) {
        sum += __shfl_xor(sum, mk);
        sq  += __shfl_xor(sq, mk);
      }
      float mu = sum * (1.f / 128.f);
      float var = sq * (1.f / 128.f) - mu * mu;
      float rs = rsqrtf(var + LN_EPS);
      const float4 g1 = *(const float4*)&g[c0];
      const float4 b1 = *(const float4*)&bb[c0];
      float gv[4] = {g1.x, g1.y, g1.z, g1.w};
      float bv[4] = {b1.x, b1.y, b1.z, b1.w};
      float zo[4];
#pragma unroll
      for (int u = 0; u < 4; ++u) {
        float z = (y[u] - mu) * rs * gv[u] + bv[u];
        zo[u] = (z > 0.f) ? z : expm1f(z);
      }
      if (l == Ln - 1) {
        if (valid) {
          float* op = &out[((size_t)(rowb + row)) * En + c0];
          *(float4*)op = make_float4(zo[0], zo[1], zo[2], zo[3]);
        }
      } else {
#pragma unroll
        for (int u = 0; u < 4; ++u) xt[row][c0 + u] = valid ? zo[u] : 0.f;
      }
    }
    __syncthreads();   // protect uni (Bs overwrite) + xt before next P1
  }
}

extern "C" void kernel_launch(void* const* d_in, const int* in_sizes, int n_in,
                              void* d_out, int out_size, void* d_ws, size_t ws_size,
                              hipStream_t stream) {
  const float* depot = (const float*)d_in[0];
  const float* node  = (const float*)d_in[1];
  const int*   adj   = (const int*)d_in[2];
  const float* depW  = (const float*)d_in[3];
  const float* depB  = (const float*)d_in[4];
  const float* nodeW = (const float*)d_in[5];
  const float* nodeB = (const float*)d_in[6];
  const float* W     = (const float*)d_in[7];
  const float* attnw = (const float*)d_in[8];
  const float* lng   = (const float*)d_in[9];
  const float* lnb   = (const float*)d_in[10];
  float* out = (float*)d_out;

  const size_t XW_ELEMS = (size_t)16 * 128 * 512;   // 1,048,576 bf16
  const size_t EJ_ELEMS = (size_t)16 * 8 * 512;     // 65,536 bf16
  unsigned short* xwT0 = (unsigned short*)d_ws;
  unsigned short* ejT0 = xwT0 + XW_ELEMS;
  unsigned short* xwT1 = ejT0 + EJ_ELEMS;
  unsigned short* ejT1 = xwT1 + XW_ELEMS;

  void* args[] = {
    (void*)&depot, (void*)&node, (void*)&adj,
    (void*)&depW, (void*)&depB, (void*)&nodeW, (void*)&nodeB,
    (void*)&W, (void*)&attnw, (void*)&lng, (void*)&lnb,
    (void*)&out, (void*)&xwT0, (void*)&ejT0, (void*)&xwT1, (void*)&ejT1
  };
  hipLaunchCooperativeKernel((const void*)mega_kernel, dim3(256), dim3(1024),
                             args, 0, stream);
}

// Round 12
// 266.565 us; speedup vs baseline: 1.7442x; 1.0559x over previous
//
#include <hip/hip_runtime.h>
#include <hip/hip_cooperative_groups.h>
#include <hip/hip_bf16.h>
#include <math.h>

namespace cg = cooperative_groups;

#define Bn 16
#define Pn 500
#define Nn 501
#define En 128
#define Hn 8
#define Ln 3
#define ROWS (Bn*Nn)   // 8016
#define LN_EPS 1e-5f

typedef __attribute__((ext_vector_type(8))) short bf16x8;
typedef __attribute__((ext_vector_type(4))) short s16x4;
typedef __attribute__((ext_vector_type(4))) float f32x4;

__device__ inline float bfu2f(unsigned short u) {
  union { unsigned u32; float f; } c; c.u32 = ((unsigned)u) << 16; return c.f;
}
__device__ inline unsigned short f2bfu(float x) {
  __hip_bfloat16 h = __float2bfloat16(x);
  union { __hip_bfloat16 hh; unsigned short u; } c; c.hh = h; return c.u;
}

// Block = (b, 32-row tile). 1024 threads = 16 waves = (head, row-group). grid 256 = 1 block/CU.
// LDS ~45 KB: xt[32][132] f32, eit[32][8], adjw[32][17], ejl[8][512] bf16, oout[32][132] f32.
__global__ __launch_bounds__(1024, 4) void mega_kernel(
    const float* __restrict__ depot, const float* __restrict__ node,
    const int* __restrict__ adj,
    const float* __restrict__ depW, const float* __restrict__ depB,
    const float* __restrict__ nodeW, const float* __restrict__ nodeB,
    const float* __restrict__ W, const float* __restrict__ attnw,
    const float* __restrict__ lng, const float* __restrict__ lnb,
    float* __restrict__ out,
    unsigned short* __restrict__ xwT0, unsigned short* __restrict__ ejT0,
    unsigned short* __restrict__ xwT1, unsigned short* __restrict__ ejT1) {
  cg::grid_group gg = cg::this_grid();

  __shared__ float xt[32][132];
  __shared__ float eit[32][8];
  __shared__ unsigned adjw[32][17];
  __shared__ unsigned short ejl[8][512];
  __shared__ float oout[32][132];

  const int blk = blockIdx.x;
  const int t = threadIdx.x;
  const int b = blk >> 4;
  const int i0 = (blk & 15) << 5;
  const int rowb = b * Nn + i0;
  const int nval = (Nn - i0) < 32 ? (Nn - i0) : 32;
  const int wave = t >> 6, lane = t & 63;
  const int li = lane & 15, lg = lane >> 4;
  const int h = wave >> 1;        // head
  const int rg = wave & 1;        // row-group
  const int r0 = rg << 4;

  // ============ P0a: adjacency bitmask pack (16 waves x 2 rows) ============
#pragma unroll
  for (int r2 = 0; r2 < 2; ++r2) {
    int r = wave * 2 + r2;
    int grow = rowb + r; if (grow >= ROWS) grow = ROWS - 1;
    const int* ar = adj + (size_t)grow * Nn;
    int v[8];
#pragma unroll
    for (int s = 0; s < 8; ++s) {
      int col = s * 64 + lane;
      v[s] = (col < Nn) ? ar[col] : 0;
    }
#pragma unroll
    for (int s = 0; s < 8; ++s) {
      unsigned long long mk = __ballot(v[s] != 0);
      if (lane == 0) {
        adjw[r][2 * s]     = (unsigned)(mk & 0xffffffffull);
        adjw[r][2 * s + 1] = (unsigned)(mk >> 32);
      }
    }
  }
  // ============ P0b: embedding -> xt ============
#pragma unroll
  for (int s = 0; s < 4; ++s) {
    int idx = t + s * 1024;         // 0..4095
    int r = idx >> 7, e = idx & 127;
    int n = i0 + r;
    float v = 0.f;
    if (r < nval) {
      if (n == 0) {
        v = depB[e] + depot[b * 2 + 0] * depW[0 * En + e]
                    + depot[b * 2 + 1] * depW[1 * En + e];
      } else {
        const float* np_ = node + ((size_t)b * Pn + (n - 1)) * 5;
        v = nodeB[e];
#pragma unroll
        for (int k = 0; k < 5; k++) v += np_[k] * nodeW[k * En + e];
      }
    }
    xt[r][e] = v;
  }

  for (int l = 0; l < Ln; ++l) {
    const float* Wl = W + (size_t)l * En * En;
    const float* al = attnw + (size_t)l * Hn * 32;
    const float* g  = lng + (size_t)l * En;
    const float* bb = lnb + (size_t)l * En;
    unsigned short* xwT = (l & 1) ? xwT1 : xwT0;
    unsigned short* ejT = (l & 1) ? ejT1 : ejT0;

    __syncthreads();   // xt ready (embed / previous LN)

    // ===== P1: xW = x @ Wl via MFMA (hi/lo x hi/lo, 3 terms); wave = (h, rg) 16x16 tile =====
    {
      f32x4 acc = {0.f, 0.f, 0.f, 0.f};
#pragma unroll
      for (int ks = 0; ks < 4; ++ks) {
        int kb = ks * 32 + lg * 8;
        f32x4 x0 = *(f32x4*)&xt[r0 + li][kb];
        f32x4 x1 = *(f32x4*)&xt[r0 + li][kb + 4];
        bf16x8 a_hi, a_lo, b_hi, b_lo;
#pragma unroll
        for (int e = 0; e < 8; ++e) {
          float v = (e < 4) ? x0[e] : x1[e - 4];
          unsigned short hu = f2bfu(v);
          a_hi[e] = (short)hu;
          a_lo[e] = (short)f2bfu(v - bfu2f(hu));
        }
#pragma unroll
        for (int e = 0; e < 8; ++e) {
          float wv = Wl[(size_t)(kb + e) * 128 + h * 16 + li];
          unsigned short hu = f2bfu(wv);
          b_hi[e] = (short)hu;
          b_lo[e] = (short)f2bfu(wv - bfu2f(hu));
        }
        acc = __builtin_amdgcn_mfma_f32_16x16x32_bf16(a_hi, b_hi, acc, 0, 0, 0);
        acc = __builtin_amdgcn_mfma_f32_16x16x32_bf16(a_hi, b_lo, acc, 0, 0, 0);
        acc = __builtin_amdgcn_mfma_f32_16x16x32_bf16(a_lo, b_hi, acc, 0, 0, 0);
      }
      __syncthreads();   // all xt (x) reads done before repurpose
      // park xW tile: rows r0 + lg*4+r, cols h*16+li
#pragma unroll
      for (int r = 0; r < 4; ++r) oout[r0 + lg * 4 + r][h * 16 + li] = acc[r];
      // transposed bf16 global write: 4 consecutive j -> one 8B store
      s16x4 pk;
#pragma unroll
      for (int r = 0; r < 4; ++r) pk[r] = (short)f2bfu(acc[r]);
      *(s16x4*)&xwT[((size_t)(b * 128 + h * 16 + li)) * 512 + i0 + r0 + lg * 4] = pk;
    }
    __syncthreads();
    // move xW from oout into xt
#pragma unroll
    for (int s = 0; s < 4; ++s) {
      int idx = t + s * 1024;
      int r = idx >> 7, e = idx & 127;
      xt[r][e] = oout[r][e];
    }
    __syncthreads();     // xt (= xW f32) ready
    // eij: ei -> eit (LDS), ej -> ejT (global bf16)
    if (t < 512) {
      int r = t >> 4, rest = t & 15, hh = rest >> 1, sel = rest & 1;
      const float* av = al + hh * 32 + sel * 16;
      float ss = 0.f;
#pragma unroll
      for (int d = 0; d < 16; ++d) ss += xt[r][hh * 16 + d] * av[d];
      if (sel) ejT[((size_t)(b * 8 + hh)) * 512 + i0 + r] = f2bfu(r < nval ? ss : 0.f);
      else     eit[r][hh] = ss;
    }
    gg.sync();   // xwT/ejT visible grid-wide

    // ================= P2: flash attention (V in registers) =================
    const unsigned short* vbase = &xwT[((size_t)(b * 128 + h * 16 + li)) * 512];
    bf16x8 vA0 = *(const bf16x8*)&vbase[lg * 8];
    bf16x8 vA1 = *(const bf16x8*)&vbase[32 + lg * 8];
    if (t < 512) {
      int hh = t >> 6, j8 = (t & 63) << 3;
      *(bf16x8*)&ejl[hh][j8] =
          *(const bf16x8*)&ejT[((size_t)(b * 8 + hh)) * 512 + j8];
    }
    __syncthreads();   // ejl ready

    {
      float eiv0 = eit[r0 + li][h];
      f32x4 acc0 = {0.f, 0.f, 0.f, 0.f};
      float m0 = -1e30f, l0 = 0.f;

      for (int jt = 0; jt < 8; ++jt) {
        bf16x8 vB0 = {}, vB1 = {};
        if (jt < 7) {   // prefetch next V pair
          vB0 = *(const bf16x8*)&vbase[(jt + 1) * 64 + lg * 8];
          vB1 = *(const bf16x8*)&vbase[(jt + 1) * 64 + 32 + lg * 8];
        }
        float sc0[2][8];
#pragma unroll
        for (int kw = 0; kw < 2; ++kw) {
          bf16x8 ev = *(bf16x8*)&ejl[h][jt * 64 + kw * 32 + lg * 8];
          unsigned mb0 = (adjw[r0 + li][(jt << 1) + kw] >> (lg << 3)) & 0xffu;
#pragma unroll
          for (int e = 0; e < 8; ++e) {
            float ejv = bfu2f((unsigned short)ev[e]);
            float s0 = eiv0 + ejv; s0 = fmaxf(s0, 0.2f * s0);
            sc0[kw][e] = ((mb0 >> e) & 1u) ? s0 : -INFINITY;
          }
        }
        float tm0 = -INFINITY;
#pragma unroll
        for (int kw = 0; kw < 2; ++kw)
#pragma unroll
          for (int e = 0; e < 8; ++e) tm0 = fmaxf(tm0, sc0[kw][e]);
        tm0 = fmaxf(tm0, __shfl_xor(tm0, 16));
        tm0 = fmaxf(tm0, __shfl_xor(tm0, 32));
        float mn0 = fmaxf(m0, tm0);
        float fr0 = __expf(m0 - mn0);
        m0 = mn0;

        float ts0 = 0.f;
        bf16x8 pah0[2], pal0[2];
#pragma unroll
        for (int kw = 0; kw < 2; ++kw)
#pragma unroll
          for (int e = 0; e < 8; ++e) {
            float p0 = __expf(sc0[kw][e] - mn0);
            ts0 += p0;
            unsigned short h0 = f2bfu(p0);
            pah0[kw][e] = (short)h0;
            pal0[kw][e] = (short)f2bfu(p0 - bfu2f(h0));
          }
        ts0 += __shfl_xor(ts0, 16);
        ts0 += __shfl_xor(ts0, 32);
        l0 = l0 * fr0 + ts0;

        int base = lg << 2;
#pragma unroll
        for (int r = 0; r < 4; ++r) acc0[r] *= __shfl(fr0, base + r);

        acc0 = __builtin_amdgcn_mfma_f32_16x16x32_bf16(pah0[0], vA0, acc0, 0, 0, 0);
        acc0 = __builtin_amdgcn_mfma_f32_16x16x32_bf16(pal0[0], vA0, acc0, 0, 0, 0);
        acc0 = __builtin_amdgcn_mfma_f32_16x16x32_bf16(pah0[1], vA1, acc0, 0, 0, 0);
        acc0 = __builtin_amdgcn_mfma_f32_16x16x32_bf16(pal0[1], vA1, acc0, 0, 0, 0);
        vA0 = vB0; vA1 = vB1;
      }
      __syncthreads();   // xW park already moved to xt; oout free for overwrite

      int base = lg << 2;
#pragma unroll
      for (int r = 0; r < 4; ++r) {
        float d0 = __shfl(l0, base + r);
        oout[r0 + base + r][h * 16 + li] = acc0[r] / d0;
      }
    }
    __syncthreads();

    // ================= LN: residual + LayerNorm + ELU =================
    {
      int row = t >> 5;
      int c0 = (t & 31) << 2;
      bool valid = row < nval;
      float4 o1 = *(float4*)&oout[row][c0];
      float4 x1 = *(float4*)&xt[row][c0];
      float y[4] = {o1.x + x1.x, o1.y + x1.y, o1.z + x1.z, o1.w + x1.w};
      float sum = 0.f, sq = 0.f;
#pragma unroll
      for (int u = 0; u < 4; ++u) { sum += y[u]; sq += y[u] * y[u]; }
#pragma unroll
      for (int mk = 1; mk <= 16; mk <<= 1) {
        sum += __shfl_xor(sum, mk);
        sq  += __shfl_xor(sq, mk);
      }
      float mu = sum * (1.f / 128.f);
      float var = sq * (1.f / 128.f) - mu * mu;
      float rs = rsqrtf(var + LN_EPS);
      const float4 g1 = *(const float4*)&g[c0];
      const float4 b1 = *(const float4*)&bb[c0];
      float gv[4] = {g1.x, g1.y, g1.z, g1.w};
      float bv[4] = {b1.x, b1.y, b1.z, b1.w};
      float zo[4];
#pragma unroll
      for (int u = 0; u < 4; ++u) {
        float z = (y[u] - mu) * rs * gv[u] + bv[u];
        zo[u] = (z > 0.f) ? z : expm1f(z);
      }
      if (l == Ln - 1) {
        if (valid) {
          float* op = &out[((size_t)(rowb + row)) * En + c0];
          *(float4*)op = make_float4(zo[0], zo[1], zo[2], zo[3]);
        }
      } else {
#pragma unroll
        for (int u = 0; u < 4; ++u) xt[row][c0 + u] = valid ? zo[u] : 0.f;
      }
    }
  }
}

extern "C" void kernel_launch(void* const* d_in, const int* in_sizes, int n_in,
                              void* d_out, int out_size, void* d_ws, size_t ws_size,
                              hipStream_t stream) {
  const float* depot = (const float*)d_in[0];
  const float* node  = (const float*)d_in[1];
  const int*   adj   = (const int*)d_in[2];
  const float* depW  = (const float*)d_in[3];
  const float* depB  = (const float*)d_in[4];
  const float* nodeW = (const float*)d_in[5];
  const float* nodeB = (const float*)d_in[6];
  const float* W     = (const float*)d_in[7];
  const float* attnw = (const float*)d_in[8];
  const float* lng   = (const float*)d_in[9];
  const float* lnb   = (const float*)d_in[10];
  float* out = (float*)d_out;

  const size_t XW_ELEMS = (size_t)16 * 128 * 512;   // 1,048,576 bf16
  const size_t EJ_ELEMS = (size_t)16 * 8 * 512;     // 65,536 bf16
  unsigned short* xwT0 = (unsigned short*)d_ws;
  unsigned short* ejT0 = xwT0 + XW_ELEMS;
  unsigned short* xwT1 = ejT0 + EJ_ELEMS;
  unsigned short* ejT1 = xwT1 + XW_ELEMS;

  void* args[] = {
    (void*)&depot, (void*)&node, (void*)&adj,
    (void*)&depW, (void*)&depB, (void*)&nodeW, (void*)&nodeB,
    (void*)&W, (void*)&attnw, (void*)&lng, (void*)&lnb,
    (void*)&out, (void*)&xwT0, (void*)&ejT0, (void*)&xwT1, (void*)&ejT1
  };
  hipLaunchCooperativeKernel((const void*)mega_kernel, dim3(256), dim3(1024),
                             args, 0, stream);
}